// Round 2
// baseline (140.409 us; speedup 1.0000x reference)
//
#include <hip/hip_runtime.h>

#define BN_EPS 1e-3f

typedef float vf4 __attribute__((ext_vector_type(4)));
typedef float f32x4 __attribute__((ext_vector_type(4)));
typedef _Float16 half8v __attribute__((ext_vector_type(8)));

// ---- order-preserving float<->uint key for atomicMax on floats ----
__device__ __forceinline__ unsigned int f2k(float f) {
    unsigned int u = __float_as_uint(f);
    return (u & 0x80000000u) ? ~u : (u | 0x80000000u);
}
__device__ __forceinline__ float k2f(unsigned int u) {
    return __uint_as_float((u & 0x80000000u) ? (u & 0x7FFFFFFFu) : ~u);
}

// Kernel 1: per-edge message via MFMA over the outer-product factorization
//   msg[e,h] = sum_k Z[e,k] * W[k,h],  K = S*F + F = 144 (padded to 160)
//   Z[e, s*F+f] = e[e,s] * x[src[e],f]  (in-register); Z[e,S*F+f] = x[src[e],f]
// One wave = one 16-edge tile x 2 tiles (front-loaded loads so both gather
// chains overlap). C layout: col = lane&15 (=h), row = (lane>>4)*4 + reg
// (=edge) -> coalesced 4-dstline x 16-channel atomic scatter. No LDS.
template <int S, int F, int H>
__global__ void __launch_bounds__(256, 6)
edge_mfma(const float* __restrict__ efeat,
          const int* __restrict__ src,
          const int* __restrict__ dst,
          const float* __restrict__ x,
          const float* __restrict__ Wk,
          const float* __restrict__ bk,
          float* __restrict__ agg,
          int E) {
    const int lane = threadIdx.x & 63;
    const int g = lane >> 4;       // k-block for A/B, row-block for C
    const int er = lane & 15;      // A: edge row; B/C: channel col

    // B fragments (W in f16, K padded to 160), built once per wave.
    half8v bfr[5];
#pragma unroll
    for (int fr = 0; fr < 5; ++fr) {
#pragma unroll
        for (int j = 0; j < 8; ++j) {
            int k = fr * 32 + g * 8 + j;
            float w = 0.f;
            if (k < S * F) w = Wk[k * H + er];
            else if (k < S * F + F) w = bk[(k - S * F) * H + er];
            bfr[fr][j] = (_Float16)w;
        }
    }

    const int TILES = (E + 15) >> 4;
    const int wid = blockIdx.x * (blockDim.x >> 6) + (threadIdx.x >> 6);
    const int t0 = wid * 2;
    if (t0 >= TILES) return;

    const int e00 = t0 << 4;
    const int e01 = e00 + 16;
    const int eA0 = min(e00 + er, E - 1);   // clamp loads; scatter guarded below
    const int eA1 = min(e01 + er, E - 1);

    // ---- front-load both tiles' scalars so the gather chains overlap ----
    int sn0 = __builtin_nontemporal_load(src + eA0);
    int sn1 = __builtin_nontemporal_load(src + eA1);

    float es0[4], es1[4];
#pragma unroll
    for (int fr = 0; fr < 4; ++fr) {
        int so = fr * 2 + (g >> 1);        // lane's k-block -> s index
        es0[fr] = __builtin_nontemporal_load(efeat + (size_t)eA0 * S + so);
        es1[fr] = __builtin_nontemporal_load(efeat + (size_t)eA1 * S + so);
    }

    const vf4* xp0 = (const vf4*)(x + (size_t)sn0 * F + (g & 1) * 8);
    const vf4* xp1 = (const vf4*)(x + (size_t)sn1 * F + (g & 1) * 8);
    vf4 xa0 = xp0[0], xb0 = xp0[1];
    vf4 xa1 = xp1[0], xb1 = xp1[1];
    float xh0[8] = {xa0.x, xa0.y, xa0.z, xa0.w, xb0.x, xb0.y, xb0.z, xb0.w};
    float xh1[8] = {xa1.x, xa1.y, xa1.z, xa1.w, xb1.x, xb1.y, xb1.z, xb1.w};

    f32x4 acc0 = {0.f, 0.f, 0.f, 0.f};
    f32x4 acc1 = {0.f, 0.f, 0.f, 0.f};
#pragma unroll
    for (int fr = 0; fr < 4; ++fr) {
        half8v a0, a1;
#pragma unroll
        for (int j = 0; j < 8; ++j) {
            a0[j] = (_Float16)(es0[fr] * xh0[j]);
            a1[j] = (_Float16)(es1[fr] * xh1[j]);
        }
        acc0 = __builtin_amdgcn_mfma_f32_16x16x32_f16(a0, bfr[fr], acc0, 0, 0, 0);
        acc1 = __builtin_amdgcn_mfma_f32_16x16x32_f16(a1, bfr[fr], acc1, 0, 0, 0);
    }
    {   // bias frag: k in [128,144) coeff 1.0 (g<2), k in [144,160) zero pad
        half8v a0, a1;
#pragma unroll
        for (int j = 0; j < 8; ++j) {
            a0[j] = (g < 2) ? (_Float16)xh0[j] : (_Float16)0.f;
            a1[j] = (g < 2) ? (_Float16)xh1[j] : (_Float16)0.f;
        }
        acc0 = __builtin_amdgcn_mfma_f32_16x16x32_f16(a0, bfr[4], acc0, 0, 0, 0);
        acc1 = __builtin_amdgcn_mfma_f32_16x16x32_f16(a1, bfr[4], acc1, 0, 0, 0);
    }

    // C[row = g*4+r][col = er] -> coalesced atomic scatter (4 lines x 64B)
#pragma unroll
    for (int r = 0; r < 4; ++r) {
        int ei = e00 + g * 4 + r;
        if (ei < E) {
            int dn = dst[ei];
            unsafeAtomicAdd(&agg[(size_t)dn * H + er], acc0[r]);
        }
    }
#pragma unroll
    for (int r = 0; r < 4; ++r) {
        int ei = e01 + g * 4 + r;
        if (ei < E) {
            int dn = dst[ei];
            unsafeAtomicAdd(&agg[(size_t)dn * H + er], acc1[r]);
        }
    }
}

// Kernel 2: h = BN(relu(agg_edges + x@Wr + br)); per-channel global max;
// the LAST block to finish (completion counter) computes the final matvec.
// All cross-block data flows through device-scope atomics (G16-safe).
template <int F, int H>
__global__ void __launch_bounds__(256)
bn_relu_max_final(const float* __restrict__ agg,
                  const float* __restrict__ x,
                  const float* __restrict__ Wr,
                  const float* __restrict__ br,
                  const float* __restrict__ gamma,
                  const float* __restrict__ beta,
                  const float* __restrict__ mmean,
                  const float* __restrict__ mvar,
                  unsigned int* __restrict__ pooled_u,
                  unsigned int* __restrict__ counter,
                  const float* __restrict__ Wd,
                  const float* __restrict__ bd,
                  float* __restrict__ out,
                  int N, int HOUT) {
    __shared__ unsigned int smax[H];
    __shared__ float pooled_s[H];
    __shared__ int is_last;
    if (threadIdx.x < H) smax[threadIdx.x] = 0u;
    __syncthreads();

    int i = blockIdx.x * blockDim.x + threadIdx.x;   // (node, 4-ch quarter)
    int h4 = (i & 3) * 4;
    float best[4] = {-INFINITY, -INFINITY, -INFINITY, -INFINITY};
    if (i < N * 4) {
        int n = i >> 2;
        const vf4* xr = (const vf4*)(x + (size_t)n * F);
        vf4 x0 = xr[0], x1 = xr[1], x2 = xr[2], x3 = xr[3];
        float xf[16] = {x0.x, x0.y, x0.z, x0.w, x1.x, x1.y, x1.z, x1.w,
                        x2.x, x2.y, x2.z, x2.w, x3.x, x3.y, x3.z, x3.w};
        vf4 basev = *(const vf4*)(br + h4);
#pragma unroll
        for (int f = 0; f < F; ++f)
            basev += xf[f] * (*(const vf4*)(Wr + f * H + h4));
        vf4 a = ((const vf4*)agg)[i];
#pragma unroll
        for (int j = 0; j < 4; ++j) {
            int h = h4 + j;
            float w = a[j] + basev[j];
            w = w > 0.f ? w : 0.f;                       // relu
            float s = gamma[h] * rsqrtf(mvar[h] + BN_EPS);
            w = w * s + (beta[h] - mmean[h] * s);        // BN (inference)
            best[j] = fmaxf(best[j], w);
        }
    }
#pragma unroll
    for (int j = 0; j < 4; ++j) atomicMax(&smax[h4 + j], f2k(best[j]));
    __syncthreads();
    if (threadIdx.x < H) atomicMax(&pooled_u[threadIdx.x], smax[threadIdx.x]);
    __syncthreads();   // drains the global atomics of all lanes (vmcnt before barrier)

    if (threadIdx.x == 0) {
        __threadfence();                                 // release
        unsigned int old = atomicAdd(counter, 1u);
        is_last = (old == gridDim.x - 1) ? 1 : 0;
    }
    __syncthreads();
    if (!is_last) return;

    __threadfence();                                     // acquire
    if (threadIdx.x < H)   // idempotent RMW: read served at the coherence point
        pooled_s[threadIdx.x] = k2f(atomicMax(&pooled_u[threadIdx.x], 0u));
    __syncthreads();
    if (threadIdx.x < HOUT) {
        float acc = bd[threadIdx.x];
#pragma unroll
        for (int hh = 0; hh < H; ++hh)
            acc += pooled_s[hh] * Wd[hh * HOUT + threadIdx.x];
        out[threadIdx.x] = acc;
    }
}

extern "C" void kernel_launch(void* const* d_in, const int* in_sizes, int n_in,
                              void* d_out, int out_size, void* d_ws, size_t ws_size,
                              hipStream_t stream) {
    const float* x     = (const float*)d_in[0];
    const float* e     = (const float*)d_in[1];
    const int*   src   = (const int*)d_in[2];
    const int*   dst   = (const int*)d_in[3];
    const float* Wk    = (const float*)d_in[4];
    const float* bk    = (const float*)d_in[5];
    const float* Wr    = (const float*)d_in[6];
    const float* br    = (const float*)d_in[7];
    const float* gamma = (const float*)d_in[8];
    const float* beta  = (const float*)d_in[9];
    const float* mmean = (const float*)d_in[10];
    const float* mvar  = (const float*)d_in[11];
    const float* Wd    = (const float*)d_in[12];
    const float* bd    = (const float*)d_in[13];

    constexpr int S = 8, F = 16, H = 16;
    const int E = in_sizes[2];
    const int N = in_sizes[0] / F;
    const int HOUT = in_sizes[13];  // 3

    // workspace: agg [N,H] fp32 | pooled_u [H] | counter [1]
    float* agg = (float*)d_ws;
    unsigned int* pooled_u = (unsigned int*)(agg + (size_t)N * H);
    unsigned int* counter  = pooled_u + H;

    // zero agg + pooled keys + counter in one stream-ordered memset
    hipMemsetAsync(d_ws, 0,
                   (size_t)N * H * sizeof(float) + (H + 1) * sizeof(unsigned int),
                   stream);

    const int T = 256;
    int TILES = (E + 15) / 16;
    int waves = (TILES + 1) / 2;            // 2 tiles per wave
    int eblocks = (waves + 3) / 4;          // 4 waves per block
    edge_mfma<S, F, H><<<eblocks, T, 0, stream>>>(e, src, dst, x, Wk, bk, agg, E);

    int bblocks = (N * 4 + T - 1) / T;
    bn_relu_max_final<F, H><<<bblocks, T, 0, stream>>>(
        agg, x, Wr, br, gamma, beta, mmean, mvar, pooled_u, counter,
        Wd, bd, (float*)d_out, N, HOUT);
}

// Round 3
// 126.989 us; speedup vs baseline: 1.1057x; 1.1057x over previous
//
#include <hip/hip_runtime.h>

#define BN_EPS 1e-3f

typedef float vf4 __attribute__((ext_vector_type(4)));
typedef float f32x4 __attribute__((ext_vector_type(4)));
typedef _Float16 half8v __attribute__((ext_vector_type(8)));

// ---- order-preserving float<->uint key for atomicMax on floats ----
__device__ __forceinline__ unsigned int f2k(float f) {
    unsigned int u = __float_as_uint(f);
    return (u & 0x80000000u) ? ~u : (u | 0x80000000u);
}
__device__ __forceinline__ float k2f(unsigned int u) {
    return __uint_as_float((u & 0x80000000u) ? (u & 0x7FFFFFFFu) : ~u);
}

// Kernel 1: per-edge message via MFMA over the outer-product factorization
//   msg[e,h] = sum_k Z[e,k] * W[k,h],  K = S*F + F = 144 (padded to 160)
//   Z[e, s*F+f] = e[e,s] * x[src[e],f]    (generated in-register)
//   Z[e, S*F+f] = x[src[e],f]             (bias part, coeff 1)
// One wave processes a 16-edge tile; grid-stride loop (~4 tiles/wave) so the
// per-wave B-fragment build amortizes. [round-1 verbatim: measured 121.7 µs;
// round-2's 2-tile unroll + 9375 short waves regressed to 140 µs, edge
// dispatch 138 µs @ 3.3% occupancy — do not re-fragment this loop]
// C layout: col = lane&15 (=h), row = (lane>>4)*4 + reg (=edge) -> coalesced
// 4-dstline x 16-channel atomic scatter. No LDS, no __syncthreads.
template <int S, int F, int H>
__global__ void __launch_bounds__(256)
edge_mfma(const float* __restrict__ efeat,
          const int* __restrict__ src,
          const int* __restrict__ dst,
          const float* __restrict__ x,
          const float* __restrict__ Wk,
          const float* __restrict__ bk,
          float* __restrict__ agg,
          int E) {
    const int lane = threadIdx.x & 63;
    const int g = lane >> 4;       // 16-lane group: k-block for A/B, row-block for C
    const int er = lane & 15;      // A: edge row within tile; B/C: channel col

    // B fragments (W in f16, K padded to 160), built once per wave.
    half8v bfr[5];
#pragma unroll
    for (int fr = 0; fr < 5; ++fr) {
#pragma unroll
        for (int j = 0; j < 8; ++j) {
            int k = fr * 32 + g * 8 + j;
            float w = 0.f;
            if (k < S * F) w = Wk[k * H + er];
            else if (k < S * F + F) w = bk[(k - S * F) * H + er];
            bfr[fr][j] = (_Float16)w;
        }
    }

    const int TILES = (E + 15) >> 4;
    int wid = blockIdx.x * (blockDim.x >> 6) + (threadIdx.x >> 6);
    int wstride = gridDim.x * (blockDim.x >> 6);

    for (int t = wid; t < TILES; t += wstride) {
        int e0 = t << 4;
        int eA = min(e0 + er, E - 1);  // clamp loads; scatter is guarded below
        int sn = __builtin_nontemporal_load(src + eA);

        // this lane's x half-row: f0 = (g&1)*8, invariant across all 5 frags
        const vf4* xp = (const vf4*)(x + (size_t)sn * F + (g & 1) * 8);
        vf4 xa = xp[0], xb = xp[1];
        float xh[8] = {xa.x, xa.y, xa.z, xa.w, xb.x, xb.y, xb.z, xb.w};

        f32x4 acc = {0.f, 0.f, 0.f, 0.f};
#pragma unroll
        for (int fr = 0; fr < 4; ++fr) {
            // lane's k-block = fr*32 + g*8  ->  s = fr*2 + (g>>1)
            float es = __builtin_nontemporal_load(
                efeat + (size_t)eA * S + fr * 2 + (g >> 1));
            half8v a;
#pragma unroll
            for (int j = 0; j < 8; ++j) a[j] = (_Float16)(es * xh[j]);
            acc = __builtin_amdgcn_mfma_f32_16x16x32_f16(a, bfr[fr], acc, 0, 0, 0);
        }
        {   // bias frag: k in [128,144) coeff 1.0 (g<2), k in [144,160) zero pad
            half8v a;
#pragma unroll
            for (int j = 0; j < 8; ++j)
                a[j] = (g < 2) ? (_Float16)xh[j] : (_Float16)0.f;
            acc = __builtin_amdgcn_mfma_f32_16x16x32_f16(a, bfr[4], acc, 0, 0, 0);
        }

        // C[row = g*4+r][col = er] -> coalesced atomic scatter
#pragma unroll
        for (int r = 0; r < 4; ++r) {
            int ei = e0 + g * 4 + r;
            if (ei < E) {
                int dn = dst[ei];
                unsafeAtomicAdd(&agg[(size_t)dn * H + er], acc[r]);
            }
        }
    }
}

// Kernel 2: h = BN(relu(agg_edges + x@Wr + br)); per-channel global max;
// the LAST block to finish (completion counter) computes the final matvec.
// All cross-block data flows through device-scope atomics (G16-safe).
template <int F, int H>
__global__ void __launch_bounds__(256)
bn_relu_max_final(const float* __restrict__ agg,
                  const float* __restrict__ x,
                  const float* __restrict__ Wr,
                  const float* __restrict__ br,
                  const float* __restrict__ gamma,
                  const float* __restrict__ beta,
                  const float* __restrict__ mmean,
                  const float* __restrict__ mvar,
                  unsigned int* __restrict__ pooled_u,
                  unsigned int* __restrict__ counter,
                  const float* __restrict__ Wd,
                  const float* __restrict__ bd,
                  float* __restrict__ out,
                  int N, int HOUT) {
    __shared__ unsigned int smax[H];
    __shared__ float pooled_s[H];
    __shared__ int is_last;
    if (threadIdx.x < H) smax[threadIdx.x] = 0u;
    __syncthreads();

    int i = blockIdx.x * blockDim.x + threadIdx.x;   // (node, 4-ch quarter)
    int h4 = (i & 3) * 4;
    float best[4] = {-INFINITY, -INFINITY, -INFINITY, -INFINITY};
    if (i < N * 4) {
        int n = i >> 2;
        const vf4* xr = (const vf4*)(x + (size_t)n * F);
        vf4 x0 = xr[0], x1 = xr[1], x2 = xr[2], x3 = xr[3];
        float xf[16] = {x0.x, x0.y, x0.z, x0.w, x1.x, x1.y, x1.z, x1.w,
                        x2.x, x2.y, x2.z, x2.w, x3.x, x3.y, x3.z, x3.w};
        vf4 basev = *(const vf4*)(br + h4);
#pragma unroll
        for (int f = 0; f < F; ++f)
            basev += xf[f] * (*(const vf4*)(Wr + f * H + h4));
        vf4 a = ((const vf4*)agg)[i];
#pragma unroll
        for (int j = 0; j < 4; ++j) {
            int h = h4 + j;
            float w = a[j] + basev[j];
            w = w > 0.f ? w : 0.f;                       // relu
            float s = gamma[h] * rsqrtf(mvar[h] + BN_EPS);
            w = w * s + (beta[h] - mmean[h] * s);        // BN (inference)
            best[j] = fmaxf(best[j], w);
        }
    }
#pragma unroll
    for (int j = 0; j < 4; ++j) atomicMax(&smax[h4 + j], f2k(best[j]));
    __syncthreads();
    if (threadIdx.x < H) atomicMax(&pooled_u[threadIdx.x], smax[threadIdx.x]);
    __syncthreads();

    if (threadIdx.x == 0) {
        __threadfence();                                 // release
        unsigned int old = atomicAdd(counter, 1u);
        is_last = (old == gridDim.x - 1) ? 1 : 0;
    }
    __syncthreads();
    if (!is_last) return;

    __threadfence();                                     // acquire
    if (threadIdx.x < H)   // idempotent RMW: read served at the coherence point
        pooled_s[threadIdx.x] = k2f(atomicMax(&pooled_u[threadIdx.x], 0u));
    __syncthreads();
    if (threadIdx.x < HOUT) {
        float acc = bd[threadIdx.x];
#pragma unroll
        for (int hh = 0; hh < H; ++hh)
            acc += pooled_s[hh] * Wd[hh * HOUT + threadIdx.x];
        out[threadIdx.x] = acc;
    }
}

extern "C" void kernel_launch(void* const* d_in, const int* in_sizes, int n_in,
                              void* d_out, int out_size, void* d_ws, size_t ws_size,
                              hipStream_t stream) {
    const float* x     = (const float*)d_in[0];
    const float* e     = (const float*)d_in[1];
    const int*   src   = (const int*)d_in[2];
    const int*   dst   = (const int*)d_in[3];
    const float* Wk    = (const float*)d_in[4];
    const float* bk    = (const float*)d_in[5];
    const float* Wr    = (const float*)d_in[6];
    const float* br    = (const float*)d_in[7];
    const float* gamma = (const float*)d_in[8];
    const float* beta  = (const float*)d_in[9];
    const float* mmean = (const float*)d_in[10];
    const float* mvar  = (const float*)d_in[11];
    const float* Wd    = (const float*)d_in[12];
    const float* bd    = (const float*)d_in[13];

    constexpr int S = 8, F = 16, H = 16;
    const int E = in_sizes[2];
    const int N = in_sizes[0] / F;
    const int HOUT = in_sizes[13];  // 3

    // workspace: agg [N,H] fp32 | pooled_u [H] | counter [1]
    float* agg = (float*)d_ws;
    unsigned int* pooled_u = (unsigned int*)(agg + (size_t)N * H);
    unsigned int* counter  = pooled_u + H;

    // zero agg + pooled keys + counter in one stream-ordered memset
    hipMemsetAsync(d_ws, 0,
                   (size_t)N * H * sizeof(float) + (H + 1) * sizeof(unsigned int),
                   stream);

    const int T = 256;
    int TILES = (E + 15) / 16;
    int eblocks = (TILES + 15) / 16;        // 4 waves/block, ~4 tiles/wave
    edge_mfma<S, F, H><<<eblocks, T, 0, stream>>>(e, src, dst, x, Wk, bk, agg, E);

    int bblocks = (N * 4 + T - 1) / T;
    bn_relu_max_final<F, H><<<bblocks, T, 0, stream>>>(
        agg, x, Wr, br, gamma, beta, mmean, mvar, pooled_u, counter,
        Wd, bd, (float*)d_out, N, HOUT);
}

// Round 4
// 122.594 us; speedup vs baseline: 1.1453x; 1.0359x over previous
//
#include <hip/hip_runtime.h>

#define BN_EPS 1e-3f

typedef float vf4 __attribute__((ext_vector_type(4)));
typedef float f32x4 __attribute__((ext_vector_type(4)));
typedef _Float16 half8v __attribute__((ext_vector_type(8)));

// ---- order-preserving float<->uint key for atomicMax on floats ----
__device__ __forceinline__ unsigned int f2k(float f) {
    unsigned int u = __float_as_uint(f);
    return (u & 0x80000000u) ? ~u : (u | 0x80000000u);
}
__device__ __forceinline__ float k2f(unsigned int u) {
    return __uint_as_float((u & 0x80000000u) ? (u & 0x7FFFFFFFu) : ~u);
}

// Kernel 1: per-edge message via MFMA over the outer-product factorization
//   msg[e,h] = sum_k Z[e,k] * W[k,h],  K = S*F + F = 144 (padded to 160)
//   Z[e, s*F+f] = e[e,s] * x[src[e],f]    (generated in-register)
//   Z[e, S*F+f] = x[src[e],f]             (bias part, coeff 1)
// One wave processes a 16-edge tile; grid-stride loop (~4 tiles/wave) so the
// per-wave B-fragment build amortizes.
// JOURNAL: this exact kernel + separate bn/matvec measured 121.7 µs (R1).
//   R2 (2-tile unroll, 9375 short waves): edge dispatch 138 µs @3.3% occ -> 140.4.
//   R3 (this kernel + fused matvec tail w/ threadfences): 127.0 -> fences cost ~5 µs.
// Do not re-fragment the loop; do not fuse the matvec.
// C layout: col = lane&15 (=h), row = (lane>>4)*4 + reg (=edge) -> coalesced
// 4-dstline x 16-channel atomic scatter. No LDS, no __syncthreads.
template <int S, int F, int H>
__global__ void __launch_bounds__(256)
edge_mfma(const float* __restrict__ efeat,
          const int* __restrict__ src,
          const int* __restrict__ dst,
          const float* __restrict__ x,
          const float* __restrict__ Wk,
          const float* __restrict__ bk,
          float* __restrict__ agg,
          int E) {
    const int lane = threadIdx.x & 63;
    const int g = lane >> 4;       // 16-lane group: k-block for A/B, row-block for C
    const int er = lane & 15;      // A: edge row within tile; B/C: channel col

    // B fragments (W in f16, K padded to 160), built once per wave.
    half8v bfr[5];
#pragma unroll
    for (int fr = 0; fr < 5; ++fr) {
#pragma unroll
        for (int j = 0; j < 8; ++j) {
            int k = fr * 32 + g * 8 + j;
            float w = 0.f;
            if (k < S * F) w = Wk[k * H + er];
            else if (k < S * F + F) w = bk[(k - S * F) * H + er];
            bfr[fr][j] = (_Float16)w;
        }
    }

    const int TILES = (E + 15) >> 4;
    int wid = blockIdx.x * (blockDim.x >> 6) + (threadIdx.x >> 6);
    int wstride = gridDim.x * (blockDim.x >> 6);

    for (int t = wid; t < TILES; t += wstride) {
        int e0 = t << 4;
        int eA = min(e0 + er, E - 1);  // clamp: loads in-bounds, scatter guarded
        int sn = __builtin_nontemporal_load(src + eA);

        // this lane's x half-row: f0 = (g&1)*8, invariant across all 5 frags
        const vf4* xp = (const vf4*)(x + (size_t)sn * F + (g & 1) * 8);
        vf4 xa = xp[0], xb = xp[1];
        float xh[8] = {xa.x, xa.y, xa.z, xa.w, xb.x, xb.y, xb.z, xb.w};

        f32x4 acc = {0.f, 0.f, 0.f, 0.f};
#pragma unroll
        for (int fr = 0; fr < 4; ++fr) {
            // lane's k-block = fr*32 + g*8  ->  s = fr*2 + (g>>1)
            float es = __builtin_nontemporal_load(
                efeat + (size_t)eA * S + fr * 2 + (g >> 1));
            half8v a;
#pragma unroll
            for (int j = 0; j < 8; ++j) a[j] = (_Float16)(es * xh[j]);
            acc = __builtin_amdgcn_mfma_f32_16x16x32_f16(a, bfr[fr], acc, 0, 0, 0);
        }
        {   // bias frag: k in [128,144) coeff 1.0 (g<2), k in [144,160) zero pad
            half8v a;
#pragma unroll
            for (int j = 0; j < 8; ++j)
                a[j] = (g < 2) ? (_Float16)xh[j] : (_Float16)0.f;
            acc = __builtin_amdgcn_mfma_f32_16x16x32_f16(a, bfr[4], acc, 0, 0, 0);
        }

        // C[row = g*4+r][col = er] -> coalesced atomic scatter
#pragma unroll
        for (int r = 0; r < 4; ++r) {
            int ei = e0 + g * 4 + r;
            if (ei < E) {
                int dn = dst[ei];
                unsafeAtomicAdd(&agg[(size_t)dn * H + er], acc[r]);
            }
        }
    }
}

// Kernel 2: h = BN(relu(agg_edges + x@Wr + br)); per-channel global max.
// Thread handles one (node, 4-channel) quarter: float4 agg load + vec base.
template <int F, int H>
__global__ void __launch_bounds__(256)
base_bn_relu_max(const float* __restrict__ agg,
                 const float* __restrict__ x,
                 const float* __restrict__ Wr,
                 const float* __restrict__ br,
                 const float* __restrict__ gamma,
                 const float* __restrict__ beta,
                 const float* __restrict__ mmean,
                 const float* __restrict__ mvar,
                 unsigned int* __restrict__ pooled_u,
                 int N) {
    __shared__ unsigned int smax[H];
    if (threadIdx.x < H) smax[threadIdx.x] = 0u;
    __syncthreads();

    int i = blockIdx.x * blockDim.x + threadIdx.x;   // (node, 4-ch quarter)
    int h4 = (i & 3) * 4;
    float best[4] = {-INFINITY, -INFINITY, -INFINITY, -INFINITY};
    if (i < N * 4) {
        int n = i >> 2;
        const vf4* xr = (const vf4*)(x + (size_t)n * F);
        vf4 x0 = xr[0], x1 = xr[1], x2 = xr[2], x3 = xr[3];
        float xf[16] = {x0.x, x0.y, x0.z, x0.w, x1.x, x1.y, x1.z, x1.w,
                        x2.x, x2.y, x2.z, x2.w, x3.x, x3.y, x3.z, x3.w};
        vf4 basev = *(const vf4*)(br + h4);
#pragma unroll
        for (int f = 0; f < F; ++f)
            basev += xf[f] * (*(const vf4*)(Wr + f * H + h4));
        vf4 a = ((const vf4*)agg)[i];
#pragma unroll
        for (int j = 0; j < 4; ++j) {
            int h = h4 + j;
            float w = a[j] + basev[j];
            w = w > 0.f ? w : 0.f;                       // relu
            float s = gamma[h] * rsqrtf(mvar[h] + BN_EPS);
            w = w * s + (beta[h] - mmean[h] * s);        // BN (inference)
            best[j] = fmaxf(best[j], w);
        }
    }
#pragma unroll
    for (int j = 0; j < 4; ++j) atomicMax(&smax[h4 + j], f2k(best[j]));
    __syncthreads();
    if (threadIdx.x < H) atomicMax(&pooled_u[threadIdx.x], smax[threadIdx.x]);
}

// Kernel 3: out[j] = bd[j] + sum_h pooled[h] * Wd[h,j]
// JOURNAL: kept as its own tiny dispatch — fusing it behind a completion
// counter (R3) cost ~5 µs in device-scope fences vs ~2 µs for this launch.
template <int H>
__global__ void final_matvec(const unsigned int* __restrict__ pooled_u,
                             const float* __restrict__ Wd,
                             const float* __restrict__ bd,
                             float* __restrict__ out,
                             int HOUT) {
    int j = threadIdx.x;
    if (j >= HOUT) return;
    float acc = bd[j];
#pragma unroll
    for (int hh = 0; hh < H; ++hh) acc += k2f(pooled_u[hh]) * Wd[hh * HOUT + j];
    out[j] = acc;
}

extern "C" void kernel_launch(void* const* d_in, const int* in_sizes, int n_in,
                              void* d_out, int out_size, void* d_ws, size_t ws_size,
                              hipStream_t stream) {
    const float* x     = (const float*)d_in[0];
    const float* e     = (const float*)d_in[1];
    const int*   src   = (const int*)d_in[2];
    const int*   dst   = (const int*)d_in[3];
    const float* Wk    = (const float*)d_in[4];
    const float* bk    = (const float*)d_in[5];
    const float* Wr    = (const float*)d_in[6];
    const float* br    = (const float*)d_in[7];
    const float* gamma = (const float*)d_in[8];
    const float* beta  = (const float*)d_in[9];
    const float* mmean = (const float*)d_in[10];
    const float* mvar  = (const float*)d_in[11];
    const float* Wd    = (const float*)d_in[12];
    const float* bd    = (const float*)d_in[13];

    constexpr int S = 8, F = 16, H = 16;
    const int E = in_sizes[2];
    const int N = in_sizes[0] / F;
    const int HOUT = in_sizes[13];  // 3

    // workspace: agg [N,H] fp32 | pooled_u [H]
    float* agg = (float*)d_ws;
    unsigned int* pooled_u = (unsigned int*)(agg + (size_t)N * H);

    // zero agg + pooled keys in one stream-ordered (capturable) memset
    hipMemsetAsync(d_ws, 0, (size_t)N * H * sizeof(float) + H * sizeof(unsigned int),
                   stream);

    const int T = 256;
    int TILES = (E + 15) / 16;
    int eblocks = (TILES + 15) / 16;        // 4 waves/block, ~4 tiles/wave
    edge_mfma<S, F, H><<<eblocks, T, 0, stream>>>(e, src, dst, x, Wk, bk, agg, E);

    int bblocks = (N * 4 + T - 1) / T;
    base_bn_relu_max<F, H><<<bblocks, T, 0, stream>>>(
        agg, x, Wr, br, gamma, beta, mmean, mvar, pooled_u, N);

    final_matvec<H><<<1, 64, 0, stream>>>(pooled_u, Wd, bd, (float*)d_out, HOUT);
}